// Round 1
// baseline (3976.581 us; speedup 1.0000x reference)
//
#include <hip/hip_runtime.h>
#include <math.h>

#define CDIM 256
#define LSEQ 8192
#define BATCH 8
#define MTOT (BATCH * LSEQ)

#define BM 64
#define BN 64
#define BK 16
#define TM 4
#define TN 4

__device__ __forceinline__ float gelu_exact(float x) {
    return 0.5f * x * (1.0f + erff(x * 0.70710678118654752440f));
}

// ---------------- feature GEMM: x (M x 256) @ f_w (256 x 516) + f_b -> q/ctx/gates ----------------
__global__ __launch_bounds__(256) void fea_gemm(
    const float* __restrict__ A, const float* __restrict__ Bw,
    const float* __restrict__ bias,
    float* __restrict__ q, float* __restrict__ ctx, float* __restrict__ gates)
{
    const int NB = 2 * CDIM + 4; // 516
    __shared__ float As[BM][BK + 1];
    __shared__ float Bs[BK][BN + 1];
    int bn = blockIdx.x * BN;
    int bm = blockIdx.y * BM;
    int tid = threadIdx.x;
    int tx = tid & 15, ty = tid >> 4;
    float acc[TM][TN] = {};
    for (int k0 = 0; k0 < CDIM; k0 += BK) {
        #pragma unroll
        for (int i = 0; i < 4; i++) {
            int lin = tid + i * 256;
            int r = lin >> 4, c = lin & 15;
            As[r][c] = A[(size_t)(bm + r) * CDIM + k0 + c];
        }
        #pragma unroll
        for (int i = 0; i < 4; i++) {
            int lin = tid + i * 256;
            int r = lin >> 6, c = lin & 63;
            int col = bn + c;
            Bs[r][c] = (col < NB) ? Bw[(size_t)(k0 + r) * NB + col] : 0.0f;
        }
        __syncthreads();
        #pragma unroll
        for (int kk = 0; kk < BK; kk++) {
            float a[TM], b[TN];
            #pragma unroll
            for (int i = 0; i < TM; i++) a[i] = As[ty * TM + i][kk];
            #pragma unroll
            for (int j = 0; j < TN; j++) b[j] = Bs[kk][tx * TN + j];
            #pragma unroll
            for (int i = 0; i < TM; i++)
                #pragma unroll
                for (int j = 0; j < TN; j++)
                    acc[i][j] += a[i] * b[j];
        }
        __syncthreads();
    }
    #pragma unroll
    for (int i = 0; i < TM; i++) {
        int t = bm + ty * TM + i;
        #pragma unroll
        for (int j = 0; j < TN; j++) {
            int n = bn + tx * TN + j;
            if (n >= NB) continue;
            float v = acc[i][j] + bias[n];
            if (n < CDIM)            q[(size_t)t * CDIM + n] = v;
            else if (n < 2 * CDIM)   ctx[(size_t)t * CDIM + (n - CDIM)] = v;
            else                     gates[(size_t)t * 4 + (n - 2 * CDIM)] = v;
        }
    }
}

// ---------------- conv1d as K shifted GEMMs: X (M x C) -> Y (M x C), +bias ----------------
__global__ __launch_bounds__(256) void conv_gemm(
    const float* __restrict__ X, const float* __restrict__ W,
    const float* __restrict__ bias, float* __restrict__ Y, int KW)
{
    __shared__ float As[BM][BK + 1];
    __shared__ float Bs[BK][BN + 1];
    int bn = blockIdx.x * BN;
    int bm = blockIdx.y * BM;
    int tid = threadIdx.x;
    int tx = tid & 15, ty = tid >> 4;
    int P = KW >> 1;
    float acc[TM][TN] = {};
    for (int k = 0; k < KW; k++) {
        int shift = k - P;
        const float* Wk = W + (size_t)k * CDIM * CDIM;
        for (int k0 = 0; k0 < CDIM; k0 += BK) {
            #pragma unroll
            for (int i = 0; i < 4; i++) {
                int lin = tid + i * 256;
                int r = lin >> 4, c = lin & 15;
                int t = bm + r;
                int tb = (t & (LSEQ - 1)) + shift;
                float v = 0.0f;
                if (tb >= 0 && tb < LSEQ)
                    v = X[(size_t)(t + shift) * CDIM + k0 + c];
                As[r][c] = v;
            }
            #pragma unroll
            for (int i = 0; i < 4; i++) {
                int lin = tid + i * 256;
                int r = lin >> 6, c = lin & 63;
                Bs[r][c] = Wk[(size_t)(k0 + r) * CDIM + bn + c];
            }
            __syncthreads();
            #pragma unroll
            for (int kk = 0; kk < BK; kk++) {
                float a[TM], b[TN];
                #pragma unroll
                for (int i = 0; i < TM; i++) a[i] = As[ty * TM + i][kk];
                #pragma unroll
                for (int j = 0; j < TN; j++) b[j] = Bs[kk][tx * TN + j];
                #pragma unroll
                for (int i = 0; i < TM; i++)
                    #pragma unroll
                    for (int j = 0; j < TN; j++)
                        acc[i][j] += a[i] * b[j];
            }
            __syncthreads();
        }
    }
    #pragma unroll
    for (int i = 0; i < TM; i++) {
        int t = bm + ty * TM + i;
        #pragma unroll
        for (int j = 0; j < TN; j++) {
            int n = bn + tx * TN + j;
            Y[(size_t)t * CDIM + n] = acc[i][j] + bias[n];
        }
    }
}

// ---------------- fused GELU + LayerNorm + gated accumulate (wave per row) ----------------
__global__ __launch_bounds__(256) void gelu_ln_acc(
    const float* __restrict__ Yconv,
    const float* __restrict__ lng, const float* __restrict__ lnb,
    const float* __restrict__ gates,
    float* __restrict__ ctx_out, float* __restrict__ ctx_all, int level)
{
    int wave = threadIdx.x >> 6;
    int lane = threadIdx.x & 63;
    int t = blockIdx.x * 4 + wave;
    const float4* src = (const float4*)(Yconv + (size_t)t * CDIM);
    float4 v = src[lane];
    float g0 = gelu_exact(v.x);
    float g1 = gelu_exact(v.y);
    float g2 = gelu_exact(v.z);
    float g3 = gelu_exact(v.w);
    float s = g0 + g1 + g2 + g3;
    float sq = g0 * g0 + g1 * g1 + g2 * g2 + g3 * g3;
    #pragma unroll
    for (int off = 32; off >= 1; off >>= 1) {
        s += __shfl_xor(s, off);
        sq += __shfl_xor(sq, off);
    }
    float mean = s * (1.0f / 256.0f);
    float var = sq * (1.0f / 256.0f) - mean * mean;
    float inv = rsqrtf(var + 1e-3f);
    float4 gw = ((const float4*)lng)[lane];
    float4 bw = ((const float4*)lnb)[lane];
    float y0 = (g0 - mean) * inv * gw.x + bw.x;
    float y1 = (g1 - mean) * inv * gw.y + bw.y;
    float y2 = (g2 - mean) * inv * gw.z + bw.z;
    float y3 = (g3 - mean) * inv * gw.w + bw.w;
    ((float4*)(ctx_out + (size_t)t * CDIM))[lane] = make_float4(y0, y1, y2, y3);
    float gate = gates[(size_t)t * 4 + level];
    float4* ca = (float4*)(ctx_all + (size_t)t * CDIM);
    if (level == 0) {
        ca[lane] = make_float4(y0 * gate, y1 * gate, y2 * gate, y3 * gate);
    } else {
        float4 p = ca[lane];
        ca[lane] = make_float4(p.x + y0 * gate, p.y + y1 * gate,
                               p.z + y2 * gate, p.w + y3 * gate);
    }
}

// ---------------- column mean over L, two-stage (deterministic) ----------------
__global__ __launch_bounds__(256) void col_mean_partial(
    const float* __restrict__ ctx, float* __restrict__ partial)
{
    int b = blockIdx.x;     // 0..7
    int chunk = blockIdx.y; // 0..31
    int c = threadIdx.x;    // 0..255
    size_t base = ((size_t)b * LSEQ + (size_t)chunk * 256) * CDIM + c;
    float s = 0.0f;
    for (int r = 0; r < 256; r++) s += ctx[base + (size_t)r * CDIM];
    partial[((size_t)b * 32 + chunk) * CDIM + c] = s;
}

__global__ __launch_bounds__(256) void col_mean_final(
    const float* __restrict__ partial, float* __restrict__ meanv)
{
    int b = blockIdx.x;
    int c = threadIdx.x;
    float s = 0.0f;
    for (int i = 0; i < 32; i++) s += partial[((size_t)b * 32 + i) * CDIM + c];
    meanv[b * CDIM + c] = s * (1.0f / (float)LSEQ);
}

// ---------------- h GEMM: A = ctx_all + mean[b]*gate3 ; Y = A @ h_w + h_b ----------------
__global__ __launch_bounds__(256) void h_gemm(
    const float* __restrict__ ctx_all, const float* __restrict__ meanv,
    const float* __restrict__ gates,
    const float* __restrict__ Bw, const float* __restrict__ bias,
    float* __restrict__ Y)
{
    __shared__ float As[BM][BK + 1];
    __shared__ float Bs[BK][BN + 1];
    int bn = blockIdx.x * BN;
    int bm = blockIdx.y * BM;
    int tid = threadIdx.x;
    int tx = tid & 15, ty = tid >> 4;
    float acc[TM][TN] = {};
    for (int k0 = 0; k0 < CDIM; k0 += BK) {
        #pragma unroll
        for (int i = 0; i < 4; i++) {
            int lin = tid + i * 256;
            int r = lin >> 4, c = lin & 15;
            int t = bm + r;
            int cc = k0 + c;
            float a = ctx_all[(size_t)t * CDIM + cc]
                    + meanv[(t >> 13) * CDIM + cc] * gates[(size_t)t * 4 + 3];
            As[r][c] = a;
        }
        #pragma unroll
        for (int i = 0; i < 4; i++) {
            int lin = tid + i * 256;
            int r = lin >> 6, c = lin & 63;
            Bs[r][c] = Bw[(size_t)(k0 + r) * CDIM + bn + c];
        }
        __syncthreads();
        #pragma unroll
        for (int kk = 0; kk < BK; kk++) {
            float a[TM], b[TN];
            #pragma unroll
            for (int i = 0; i < TM; i++) a[i] = As[ty * TM + i][kk];
            #pragma unroll
            for (int j = 0; j < TN; j++) b[j] = Bs[kk][tx * TN + j];
            #pragma unroll
            for (int i = 0; i < TM; i++)
                #pragma unroll
                for (int j = 0; j < TN; j++)
                    acc[i][j] += a[i] * b[j];
        }
        __syncthreads();
    }
    #pragma unroll
    for (int i = 0; i < TM; i++) {
        int t = bm + ty * TM + i;
        #pragma unroll
        for (int j = 0; j < TN; j++) {
            int n = bn + tx * TN + j;
            Y[(size_t)t * CDIM + n] = acc[i][j] + bias[n];
        }
    }
}

// ---------------- out GEMM: A = q .* ctx_h ; out = A @ proj_w + proj_b ----------------
__global__ __launch_bounds__(256) void out_gemm(
    const float* __restrict__ q, const float* __restrict__ ctxh,
    const float* __restrict__ Bw, const float* __restrict__ bias,
    float* __restrict__ Y)
{
    __shared__ float As[BM][BK + 1];
    __shared__ float Bs[BK][BN + 1];
    int bn = blockIdx.x * BN;
    int bm = blockIdx.y * BM;
    int tid = threadIdx.x;
    int tx = tid & 15, ty = tid >> 4;
    float acc[TM][TN] = {};
    for (int k0 = 0; k0 < CDIM; k0 += BK) {
        #pragma unroll
        for (int i = 0; i < 4; i++) {
            int lin = tid + i * 256;
            int r = lin >> 4, c = lin & 15;
            size_t idx = (size_t)(bm + r) * CDIM + k0 + c;
            As[r][c] = q[idx] * ctxh[idx];
        }
        #pragma unroll
        for (int i = 0; i < 4; i++) {
            int lin = tid + i * 256;
            int r = lin >> 6, c = lin & 63;
            Bs[r][c] = Bw[(size_t)(k0 + r) * CDIM + bn + c];
        }
        __syncthreads();
        #pragma unroll
        for (int kk = 0; kk < BK; kk++) {
            float a[TM], b[TN];
            #pragma unroll
            for (int i = 0; i < TM; i++) a[i] = As[ty * TM + i][kk];
            #pragma unroll
            for (int j = 0; j < TN; j++) b[j] = Bs[kk][tx * TN + j];
            #pragma unroll
            for (int i = 0; i < TM; i++)
                #pragma unroll
                for (int j = 0; j < TN; j++)
                    acc[i][j] += a[i] * b[j];
        }
        __syncthreads();
    }
    #pragma unroll
    for (int i = 0; i < TM; i++) {
        int t = bm + ty * TM + i;
        #pragma unroll
        for (int j = 0; j < TN; j++) {
            int n = bn + tx * TN + j;
            Y[(size_t)t * CDIM + n] = acc[i][j] + bias[n];
        }
    }
}

extern "C" void kernel_launch(void* const* d_in, const int* in_sizes, int n_in,
                              void* d_out, int out_size, void* d_ws, size_t ws_size,
                              hipStream_t stream) {
    const float* x      = (const float*)d_in[0];
    const float* f_w    = (const float*)d_in[1];
    const float* f_b    = (const float*)d_in[2];
    const float* h_w    = (const float*)d_in[3];
    const float* h_b    = (const float*)d_in[4];
    const float* proj_w = (const float*)d_in[5];
    const float* proj_b = (const float*)d_in[6];
    const float* conv_w[3] = { (const float*)d_in[7],  (const float*)d_in[11], (const float*)d_in[15] };
    const float* conv_b[3] = { (const float*)d_in[8],  (const float*)d_in[12], (const float*)d_in[16] };
    const float* ln_g[3]   = { (const float*)d_in[9],  (const float*)d_in[13], (const float*)d_in[17] };
    const float* ln_b[3]   = { (const float*)d_in[10], (const float*)d_in[14], (const float*)d_in[18] };

    const size_t MC = (size_t)MTOT * CDIM; // 16,777,216
    float* ws = (float*)d_ws;
    float* q       = ws;
    float* ctxA    = q + MC;
    float* ctxB    = ctxA + MC;
    float* gates   = ctxB + MC;          // MTOT*4
    float* partial = gates + (size_t)MTOT * 4; // 8*32*256
    float* meanv   = partial + 8 * 32 * CDIM;  // 8*256
    float* ctx_all = (float*)d_out;      // reuse output buffer as accumulator

    dim3 blk(256);
    dim3 gridFea((2 * CDIM + 4 + BN - 1) / BN, MTOT / BM); // (9, 1024)
    dim3 gridSq(CDIM / BN, MTOT / BM);                     // (4, 1024)

    // 1. feature GEMM -> q, ctxA, gates
    fea_gemm<<<gridFea, blk, 0, stream>>>(x, f_w, f_b, q, ctxA, gates);

    // 2-7. three conv+GELU+LN+accumulate levels (ping-pong ctxA/ctxB)
    conv_gemm<<<gridSq, blk, 0, stream>>>(ctxA, conv_w[0], conv_b[0], ctxB, 3);
    gelu_ln_acc<<<dim3(MTOT / 4), blk, 0, stream>>>(ctxB, ln_g[0], ln_b[0], gates, ctxB, ctx_all, 0);

    conv_gemm<<<gridSq, blk, 0, stream>>>(ctxB, conv_w[1], conv_b[1], ctxA, 5);
    gelu_ln_acc<<<dim3(MTOT / 4), blk, 0, stream>>>(ctxA, ln_g[1], ln_b[1], gates, ctxA, ctx_all, 1);

    conv_gemm<<<gridSq, blk, 0, stream>>>(ctxA, conv_w[2], conv_b[2], ctxB, 7);
    gelu_ln_acc<<<dim3(MTOT / 4), blk, 0, stream>>>(ctxB, ln_g[2], ln_b[2], gates, ctxB, ctx_all, 2);

    // 8-9. mean over L of final ctx (ctxB) -> meanv
    col_mean_partial<<<dim3(BATCH, 32), blk, 0, stream>>>(ctxB, partial);
    col_mean_final<<<dim3(BATCH), blk, 0, stream>>>(partial, meanv);

    // 10. h GEMM (fused global-context add) -> ctxA
    h_gemm<<<gridSq, blk, 0, stream>>>(ctx_all, meanv, gates, h_w, h_b, ctxA);

    // 11. final projection GEMM (fused q .* ctx) -> d_out
    out_gemm<<<gridSq, blk, 0, stream>>>(q, ctxA, proj_w, proj_b, (float*)d_out);
}

// Round 2
// 554.607 us; speedup vs baseline: 7.1701x; 7.1701x over previous
//
#include <hip/hip_runtime.h>
#include <math.h>

#define CDIM 256
#define LSEQ 8192
#define BATCH 8
#define MTOT (BATCH * LSEQ)
#define PADROWS 8208           // 8 + 8192 + 8 per batch
#define PAD0 8

typedef unsigned short ushort_t;
typedef unsigned int uint_t;

typedef __bf16 bf16x8 __attribute__((ext_vector_type(8)));
typedef float f32x4 __attribute__((ext_vector_type(4)));

__device__ __forceinline__ ushort_t f2bf(float f) {
    union { float f; uint_t u; } v; v.f = f;
    uint_t u = v.u;
    return (ushort_t)((u + 0x7FFFu + ((u >> 16) & 1u)) >> 16);  // RNE
}
__device__ __forceinline__ float bf2f(ushort_t h) {
    union { uint_t u; float f; } v; v.u = ((uint_t)h) << 16;
    return v.f;
}
__device__ __forceinline__ float gelu_exact(float x) {
    return 0.5f * x * (1.0f + erff(x * 0.70710678118654752440f));
}

// async global(16B/lane) -> LDS (wave-uniform base + lane*16)
__device__ __forceinline__ void gload16(const ushort_t* g, ushort_t* lds) {
    __builtin_amdgcn_global_load_lds(
        reinterpret_cast<__attribute__((address_space(1))) uint_t*>(
            reinterpret_cast<uintptr_t>(g)),
        reinterpret_cast<__attribute__((address_space(3))) uint_t*>(
            reinterpret_cast<uintptr_t>(lds)),
        16, 0, 0);
}

// ---------------- fp32 -> bf16 convert ----------------
__global__ __launch_bounds__(256) void cvt_f32_bf16(const float* __restrict__ in,
                                                    ushort_t* __restrict__ out) {
    int i = blockIdx.x * 256 + threadIdx.x;   // one float4 per thread
    float4 v = ((const float4*)in)[i];
    ushort4 o = { f2bf(v.x), f2bf(v.y), f2bf(v.z), f2bf(v.w) };
    ((ushort4*)out)[i] = o;
}

// ---------------- transpose + convert: out[n*K+k] = bf16(in[k*ldin+col0+n]) ----------------
__global__ __launch_bounds__(256) void transpose_cvt(const float* __restrict__ in,
                                                     ushort_t* __restrict__ out,
                                                     int K, int N, int ldin, int col0) {
    __shared__ float t[32][33];
    int k0 = blockIdx.x * 32, n0 = blockIdx.y * 32;
    int tx = threadIdx.x, ty = threadIdx.y;   // (32,8)
    #pragma unroll
    for (int i = 0; i < 4; i++) {
        int k = k0 + ty + i * 8;
        t[ty + i * 8][tx] = in[(size_t)k * ldin + col0 + n0 + tx];
    }
    __syncthreads();
    #pragma unroll
    for (int i = 0; i < 4; i++) {
        int n = n0 + ty + i * 8;
        out[(size_t)n * K + k0 + tx] = f2bf(t[tx][ty + i * 8]);
    }
}

// ---------------- zero the guard bands of ctx_pad ----------------
__global__ __launch_bounds__(256) void zero_guards(ushort_t* __restrict__ ctx_pad) {
    int i = blockIdx.x * 256 + threadIdx.x;   // 8*16*256 = 32768
    int c = i & 255;
    int r = (i >> 8) & 15;
    int b = i >> 12;
    int row = b * PADROWS + ((r < 8) ? r : (PADROWS - 16 + r));
    ctx_pad[(size_t)row * CDIM + c] = 0;
}

// ---------------- MFMA GEMM (m97 structure): 128x128 tile, K-step 32 ----------------
// A: bf16 [rows][256] (possibly batch-padded), BT: bf16 [N][Ktot], out fp32 or split bf16.
// MODE 0: C[row*256+col] = acc + bias   (N=256 grid.x=2)
// MODE 1: fea: col<256 -> q_bf ; col>=256 -> ctx_pad (padded rows)   (N=512 grid.x=4)
template <int MODE>
__global__ __launch_bounds__(256) void gemm_bf16(
    const ushort_t* __restrict__ A, const ushort_t* __restrict__ BT,
    const float* __restrict__ bias,
    float* __restrict__ C, ushort_t* __restrict__ q_out, ushort_t* __restrict__ ctx_pad,
    int Ktot, int koff, int tiles_per_batch, int batch_stride_rows, int row0)
{
    __shared__ __align__(16) ushort_t As[128 * 32];
    __shared__ __align__(16) ushort_t Bs[128 * 32];
    int tid = threadIdx.x;
    int w = tid >> 6, l = tid & 63;
    int bn = blockIdx.x * 128;
    int by = blockIdx.y;
    int b = by / tiles_per_batch;
    int tloc = (by % tiles_per_batch) * 128;
    long arow0 = (long)b * batch_stride_rows + row0 + tloc;
    int crow0 = by * 128;

    int wr = w >> 1, wc = w & 1;
    int lr = l & 15, lk = (l >> 4) * 8;
    int sr = l >> 2;            // staging row within 16-row chunk
    int sc = (l & 3) * 8;       // staging col (bf16 elems)

    f32x4 acc[4][4] = {};

    int nsteps = Ktot >> 5;
    for (int kt = 0; kt < nsteps; ++kt) {
        int k0 = kt << 5;
        #pragma unroll
        for (int jj = 0; jj < 2; ++jj) {
            int j = w * 2 + jj;
            int r = j * 16 + sr;
            const ushort_t* ga = A + (long)(arow0 + r) * CDIM + (koff + k0 + sc);
            gload16(ga, &As[j * 512]);
            const ushort_t* gb = BT + (long)(bn + r) * Ktot + (k0 + sc);
            gload16(gb, &Bs[j * 512]);
        }
        __syncthreads();
        bf16x8 av[4], bv[4];
        #pragma unroll
        for (int m = 0; m < 4; ++m)
            av[m] = *reinterpret_cast<const bf16x8*>(&As[(wr * 64 + m * 16 + lr) * 32 + lk]);
        #pragma unroll
        for (int n = 0; n < 4; ++n)
            bv[n] = *reinterpret_cast<const bf16x8*>(&Bs[(wc * 64 + n * 16 + lr) * 32 + lk]);
        #pragma unroll
        for (int m = 0; m < 4; ++m)
            #pragma unroll
            for (int n = 0; n < 4; ++n)
                acc[m][n] = __builtin_amdgcn_mfma_f32_16x16x32_bf16(av[m], bv[n], acc[m][n], 0, 0, 0);
        __syncthreads();
    }

    int rbase = (l >> 4) * 4;
    #pragma unroll
    for (int n = 0; n < 4; ++n) {
        int col = bn + wc * 64 + n * 16 + lr;
        float bia = bias[col];
        #pragma unroll
        for (int m = 0; m < 4; ++m) {
            int rowb = crow0 + wr * 64 + m * 16 + rbase;
            #pragma unroll
            for (int r = 0; r < 4; ++r) {
                float v = acc[m][n][r] + bia;
                int row = rowb + r;
                if (MODE == 0) {
                    C[(size_t)row * CDIM + col] = v;
                } else {
                    if (col < CDIM) {
                        q_out[(size_t)row * CDIM + col] = f2bf(v);
                    } else {
                        int bb = row >> 13, tb = row & (LSEQ - 1);
                        ctx_pad[((size_t)bb * PADROWS + PAD0 + tb) * CDIM + (col - CDIM)] = f2bf(v);
                    }
                }
            }
        }
    }
}

// ---------------- gates sliver: gates[t][j] = x[t]·f_w[:,512+j] + f_b[512+j] ----------------
__global__ __launch_bounds__(256) void gates_kernel(const float* __restrict__ x,
                                                    const float* __restrict__ f_w,
                                                    const float* __restrict__ f_b,
                                                    float* __restrict__ gates) {
    __shared__ float fcol[256][4];
    int tid = threadIdx.x;
    #pragma unroll
    for (int j = 0; j < 4; ++j) fcol[tid][j] = f_w[(size_t)tid * 516 + 512 + j];
    __syncthreads();
    int w = tid >> 6, l = tid & 63;
    int t = blockIdx.x * 4 + w;
    float4 xv = ((const float4*)(x + (size_t)t * CDIM))[l];
    int c = l * 4;
    float a[4];
    #pragma unroll
    for (int j = 0; j < 4; ++j)
        a[j] = xv.x * fcol[c][j] + xv.y * fcol[c + 1][j] + xv.z * fcol[c + 2][j] + xv.w * fcol[c + 3][j];
    #pragma unroll
    for (int off = 32; off >= 1; off >>= 1)
        #pragma unroll
        for (int j = 0; j < 4; ++j) a[j] += __shfl_xor(a[j], off);
    if (l == 0) {
        #pragma unroll
        for (int j = 0; j < 4; ++j) gates[(size_t)t * 4 + j] = a[j] + f_b[512 + j];
    }
}

// ---------------- fused GELU + LayerNorm + gated accumulate ----------------
__global__ __launch_bounds__(256) void gelu_ln_acc(
    const float* __restrict__ Yconv,
    const float* __restrict__ lng, const float* __restrict__ lnb,
    const float* __restrict__ gates,
    ushort_t* __restrict__ ctx_pad, float* __restrict__ ctx_all, int level)
{
    int wave = threadIdx.x >> 6;
    int lane = threadIdx.x & 63;
    int t = blockIdx.x * 4 + wave;
    float4 v = ((const float4*)(Yconv + (size_t)t * CDIM))[lane];
    float g0 = gelu_exact(v.x), g1 = gelu_exact(v.y);
    float g2 = gelu_exact(v.z), g3 = gelu_exact(v.w);
    float s = g0 + g1 + g2 + g3;
    float sq = g0 * g0 + g1 * g1 + g2 * g2 + g3 * g3;
    #pragma unroll
    for (int off = 32; off >= 1; off >>= 1) {
        s += __shfl_xor(s, off);
        sq += __shfl_xor(sq, off);
    }
    float mean = s * (1.0f / 256.0f);
    float var = sq * (1.0f / 256.0f) - mean * mean;
    float inv = rsqrtf(var + 1e-3f);
    float4 gw = ((const float4*)lng)[lane];
    float4 bw = ((const float4*)lnb)[lane];
    float y0 = (g0 - mean) * inv * gw.x + bw.x;
    float y1 = (g1 - mean) * inv * gw.y + bw.y;
    float y2 = (g2 - mean) * inv * gw.z + bw.z;
    float y3 = (g3 - mean) * inv * gw.w + bw.w;
    int b = t >> 13, tb = t & (LSEQ - 1);
    ushort4 o = { f2bf(y0), f2bf(y1), f2bf(y2), f2bf(y3) };
    ((ushort4*)(ctx_pad + ((size_t)b * PADROWS + PAD0 + tb) * CDIM))[lane] = o;
    float gate = gates[(size_t)t * 4 + level];
    float4* ca = (float4*)(ctx_all + (size_t)t * CDIM) + lane;
    if (level == 0) {
        *ca = make_float4(y0 * gate, y1 * gate, y2 * gate, y3 * gate);
    } else {
        float4 p = *ca;
        *ca = make_float4(p.x + y0 * gate, p.y + y1 * gate, p.z + y2 * gate, p.w + y3 * gate);
    }
}

// ---------------- column mean over L (two stage), input bf16 padded ----------------
__global__ __launch_bounds__(256) void col_mean_partial(const ushort_t* __restrict__ ctx_pad,
                                                        float* __restrict__ partial) {
    int b = blockIdx.x, chunk = blockIdx.y, c = threadIdx.x;
    const ushort_t* base = ctx_pad + ((size_t)b * PADROWS + PAD0 + chunk * 256) * CDIM + c;
    float s = 0.0f;
    for (int r = 0; r < 256; ++r) s += bf2f(base[(size_t)r * CDIM]);
    partial[((size_t)b * 32 + chunk) * CDIM + c] = s;
}

__global__ __launch_bounds__(256) void col_mean_final(const float* __restrict__ partial,
                                                      float* __restrict__ meanv) {
    int b = blockIdx.x, c = threadIdx.x;
    float s = 0.0f;
    for (int i = 0; i < 32; ++i) s += partial[((size_t)b * 32 + i) * CDIM + c];
    meanv[b * CDIM + c] = s * (1.0f / (float)LSEQ);
}

// ---------------- A_bf = bf16(ctx_all + meanv[b]*gate3) ----------------
__global__ __launch_bounds__(256) void finalize_A(const float* __restrict__ ctx_all,
                                                  const float* __restrict__ meanv,
                                                  const float* __restrict__ gates,
                                                  ushort_t* __restrict__ A_bf) {
    int i = blockIdx.x * 256 + threadIdx.x;  // one float4 group
    int t = i >> 6;
    int c4 = (i & 63) * 4;
    int b = t >> 13;
    float g3 = gates[(size_t)t * 4 + 3];
    float4 v = ((const float4*)ctx_all)[i];
    const float* mv = meanv + b * CDIM + c4;
    v.x += mv[0] * g3; v.y += mv[1] * g3; v.z += mv[2] * g3; v.w += mv[3] * g3;
    ushort4 o = { f2bf(v.x), f2bf(v.y), f2bf(v.z), f2bf(v.w) };
    ((ushort4*)A_bf)[i] = o;
}

// ---------------- qc_bf = bf16(q_bf * ctxh) ----------------
__global__ __launch_bounds__(256) void qc_mul(const ushort_t* __restrict__ q_bf,
                                              const float* __restrict__ ctxh,
                                              ushort_t* __restrict__ qc_bf) {
    int i = blockIdx.x * 256 + threadIdx.x;
    ushort4 qb = ((const ushort4*)q_bf)[i];
    float4 cv = ((const float4*)ctxh)[i];
    ushort4 o = { f2bf(bf2f(qb.x) * cv.x), f2bf(bf2f(qb.y) * cv.y),
                  f2bf(bf2f(qb.z) * cv.z), f2bf(bf2f(qb.w) * cv.w) };
    ((ushort4*)qc_bf)[i] = o;
}

extern "C" void kernel_launch(void* const* d_in, const int* in_sizes, int n_in,
                              void* d_out, int out_size, void* d_ws, size_t ws_size,
                              hipStream_t stream) {
    const float* x      = (const float*)d_in[0];
    const float* f_w    = (const float*)d_in[1];
    const float* f_b    = (const float*)d_in[2];
    const float* h_w    = (const float*)d_in[3];
    const float* h_b    = (const float*)d_in[4];
    const float* proj_w = (const float*)d_in[5];
    const float* proj_b = (const float*)d_in[6];
    const float* conv_w[3] = { (const float*)d_in[7],  (const float*)d_in[11], (const float*)d_in[15] };
    const float* conv_b[3] = { (const float*)d_in[8],  (const float*)d_in[12], (const float*)d_in[16] };
    const float* ln_g[3]   = { (const float*)d_in[9],  (const float*)d_in[13], (const float*)d_in[17] };
    const float* ln_b[3]   = { (const float*)d_in[10], (const float*)d_in[14], (const float*)d_in[18] };

    const size_t MC = (size_t)MTOT * CDIM;
    char* w = (char*)d_ws;
    ushort_t* x_bf   = (ushort_t*)w;  w += MC * 2;
    ushort_t* q_bf   = (ushort_t*)w;  w += MC * 2;
    float* conv_out  = (float*)w;     w += MC * 4;
    ushort_t* ctx_pad = (ushort_t*)w; w += (size_t)BATCH * PADROWS * CDIM * 2;
    float* gates     = (float*)w;     w += (size_t)MTOT * 4 * 4;
    float* partial   = (float*)w;     w += (size_t)8 * 32 * CDIM * 4;
    float* meanv     = (float*)w;     w += (size_t)8 * CDIM * 4;
    ushort_t* f_wT   = (ushort_t*)w;  w += (size_t)512 * 256 * 2;
    ushort_t* convT0 = (ushort_t*)w;  w += (size_t)768 * 256 * 2;
    ushort_t* convT1 = (ushort_t*)w;  w += (size_t)1280 * 256 * 2;
    ushort_t* convT2 = (ushort_t*)w;  w += (size_t)1792 * 256 * 2;
    ushort_t* h_wT   = (ushort_t*)w;  w += (size_t)256 * 256 * 2;
    ushort_t* proj_wT = (ushort_t*)w; w += (size_t)256 * 256 * 2;
    ushort_t* A_bf  = x_bf;   // reuse (x consumed after fea+gates)
    ushort_t* qc_bf = x_bf;   // reuse (A_bf consumed after h_gemm)
    float* ctxh     = conv_out; // reuse (conv_out consumed after level2 gelu_ln)
    float* ctx_all  = (float*)d_out;

    dim3 blk(256);
    dim3 t8(32, 8);

    // weight prep + x conversion
    cvt_f32_bf16<<<dim3(MC / 4 / 256), blk, 0, stream>>>(x, x_bf);
    transpose_cvt<<<dim3(8, 16), t8, 0, stream>>>(f_w, f_wT, 256, 512, 516, 0);
    transpose_cvt<<<dim3(24, 8), t8, 0, stream>>>(conv_w[0], convT0, 768, 256, 256, 0);
    transpose_cvt<<<dim3(40, 8), t8, 0, stream>>>(conv_w[1], convT1, 1280, 256, 256, 0);
    transpose_cvt<<<dim3(56, 8), t8, 0, stream>>>(conv_w[2], convT2, 1792, 256, 256, 0);
    transpose_cvt<<<dim3(8, 8), t8, 0, stream>>>(h_w, h_wT, 256, 256, 256, 0);
    transpose_cvt<<<dim3(8, 8), t8, 0, stream>>>(proj_w, proj_wT, 256, 256, 256, 0);
    zero_guards<<<dim3(128), blk, 0, stream>>>(ctx_pad);

    // feature GEMM (q + ctx) and gates sliver
    gemm_bf16<1><<<dim3(4, 512), blk, 0, stream>>>(x_bf, f_wT, f_b,
        nullptr, q_bf, ctx_pad, 256, 0, 512, 0, 0);
    gates_kernel<<<dim3(MTOT / 4), blk, 0, stream>>>(x, f_w, f_b, gates);

    // three conv + GELU/LN/gate levels (ctx_pad updated in place by gelu_ln)
    const ushort_t* convT[3] = { convT0, convT1, convT2 };
    const int KT[3] = { 768, 1280, 1792 };
    const int KOFF[3] = { -256, -512, -768 };
    for (int l = 0; l < 3; ++l) {
        gemm_bf16<0><<<dim3(2, 512), blk, 0, stream>>>(ctx_pad, convT[l], conv_b[l],
            conv_out, nullptr, nullptr, KT[l], KOFF[l], 64, PADROWS, PAD0);
        gelu_ln_acc<<<dim3(MTOT / 4), blk, 0, stream>>>(conv_out, ln_g[l], ln_b[l],
            gates, ctx_pad, ctx_all, l);
    }

    // global context mean
    col_mean_partial<<<dim3(BATCH, 32), blk, 0, stream>>>(ctx_pad, partial);
    col_mean_final<<<dim3(BATCH), blk, 0, stream>>>(partial, meanv);

    // h GEMM input: ctx_all + mean*gate3 (bf16)
    finalize_A<<<dim3(MC / 4 / 256), blk, 0, stream>>>(ctx_all, meanv, gates, A_bf);
    gemm_bf16<0><<<dim3(2, 512), blk, 0, stream>>>(A_bf, h_wT, h_b,
        ctxh, nullptr, nullptr, 256, 0, 512, 0, 0);

    // final projection: (q .* ctxh) @ proj_w
    qc_mul<<<dim3(MC / 4 / 256), blk, 0, stream>>>(q_bf, ctxh, qc_bf);
    gemm_bf16<0><<<dim3(2, 512), blk, 0, stream>>>(qc_bf, proj_wT, proj_b,
        (float*)d_out, nullptr, nullptr, 256, 0, 512, 0, 0);
}